// Round 7
// baseline (233.667 us; speedup 1.0000x reference)
//
#include <hip/hip_runtime.h>

#define NN 500
#define BB 32
#define TT 12
#define EMB 10

// ---------------- K1: S = softmax(relu(E E^T) with diag=stay), rows ----------------
__global__ __launch_bounds__(256) void k_softmaxS(const float* __restrict__ E,
                                                  const int* __restrict__ stay,
                                                  float* __restrict__ S) {
    const int i = blockIdx.x;
    const int tid = threadIdx.x;
    __shared__ float row[NN];
    __shared__ float red[256];
    float ei[EMB];
#pragma unroll
    for (int d = 0; d < EMB; ++d) ei[d] = E[i * EMB + d];
    const float stayf = (float)stay[0];

    float lmax = -1e30f;
    for (int j = tid; j < NN; j += 256) {
        float acc = 0.f;
#pragma unroll
        for (int d = 0; d < EMB; ++d) acc += ei[d] * E[j * EMB + d];
        float v = acc > 0.f ? acc : 0.f;
        if (j == i) v = stayf;
        row[j] = v;
        lmax = fmaxf(lmax, v);
    }
    red[tid] = lmax;
    __syncthreads();
    for (int s = 128; s > 0; s >>= 1) {
        if (tid < s) red[tid] = fmaxf(red[tid], red[tid + s]);
        __syncthreads();
    }
    const float rmax = red[0];
    __syncthreads();

    float lsum = 0.f;
    for (int j = tid; j < NN; j += 256) {
        float e = __expf(row[j] - rmax);
        row[j] = e;
        lsum += e;
    }
    red[tid] = lsum;
    __syncthreads();
    for (int s = 128; s > 0; s >>= 1) {
        if (tid < s) red[tid] += red[tid + s];
        __syncthreads();
    }
    const float inv = 1.0f / red[0];
    for (int j = tid; j < NN; j += 256) S[i * NN + j] = row[j] * inv;
}

// ---------------- K2/K3: y[b,n] = sum_m S[n,m] * xin[b,m] (wave per row) ----------------
__global__ __launch_bounds__(256) void k_matvecS(const float* __restrict__ S,
                                                 const float* __restrict__ xin,
                                                 float* __restrict__ yout) {
    const int b = blockIdx.y;
    const int w = threadIdx.x >> 6;
    const int lane = threadIdx.x & 63;
    const int n = blockIdx.x * 4 + w;
    const float* xb = xin + b * NN;
    const float* Sr = S + n * NN;
    float acc = 0.f;
    for (int m = lane; m < NN; m += 64) acc += Sr[m] * xb[m];
#pragma unroll
    for (int off = 32; off > 0; off >>= 1) acc += __shfl_down(acc, off, 64);
    if (lane == 0) yout[b * NN + n] = acc;
}

// ---------------- K4: per-node small weights from embeddings ----------------
__global__ __launch_bounds__(256) void k_smallpre(const float* __restrict__ E,
                                                  const float* __restrict__ wp,
                                                  const float* __restrict__ bp,
                                                  const float* __restrict__ wwsp,
                                                  const float* __restrict__ wwtp,
                                                  float* __restrict__ W,
                                                  float* __restrict__ biasN,
                                                  float* __restrict__ wws,
                                                  float* __restrict__ wwt) {
    const int n = blockIdx.x;
    const int tid = threadIdx.x;
    __shared__ float e[EMB];
    if (tid < EMB) e[tid] = E[n * EMB + tid];
    __syncthreads();
    if (tid < 144) {
        float acc = 0.f;
#pragma unroll
        for (int d = 0; d < EMB; ++d) acc += e[d] * wp[d * 144 + tid];
        W[n * 144 + tid] = acc;
    } else if (tid < 208) {
        const int o = tid - 144;
        float acc = 0.f;
#pragma unroll
        for (int d = 0; d < EMB; ++d) acc += e[d] * bp[d * 64 + o];
        biasN[n * 64 + o] = acc;
    } else if (tid < 216) {
        const int o = tid - 208;
        float acc = 0.f;
#pragma unroll
        for (int d = 0; d < EMB; ++d) acc += e[d] * wwsp[d * 8 + o];
        wws[n * 8 + o] = acc;
    } else if (tid < 224) {
        const int o = tid - 216;
        float acc = 0.f;
#pragma unroll
        for (int d = 0; d < EMB; ++d) acc += e[d] * wwtp[d * 8 + o];
        wwt[n * 8 + o] = acc;
    }
}

// ---------------- K5: M[b,n] = mean_f xws, wsum[b,n] = sum_t xw[b,t,n]*T[t] ----------------
__global__ __launch_bounds__(128) void k_Mwsum(const float* __restrict__ xwin,
                                               const float* __restrict__ S,
                                               const int* __restrict__ bidx,
                                               const int* __restrict__ jumpc,
                                               const float* __restrict__ Tp,
                                               float* __restrict__ M,
                                               float* __restrict__ wsum) {
    const int b = blockIdx.y;
    const int n0 = blockIdx.x * 125;
    const int tid = threadIdx.x;
    __shared__ float xsf[NN];
    __shared__ float Tl[TT];
    const int t0 = bidx[0], t1 = bidx[1], t2 = bidx[2];
    if (tid < TT) Tl[tid] = Tp[tid];
    const float* xb = xwin + (size_t)b * TT * NN;
    for (int m = tid; m < NN; m += 128)
        xsf[m] = xb[t0 * NN + m] + xb[t1 * NN + m] + xb[t2 * NN + m];
    __syncthreads();
    if (tid < 125) {
        const int n = n0 + tid;
        float ws_ = 0.f;
#pragma unroll
        for (int t = 0; t < TT; ++t) ws_ += xb[t * NN + n] * Tl[t];
        const float jc = (float)jumpc[0];
        const float jterm = jc * (2.f * xb[t0 * NN + n] + xb[t1 * NN + n]);
        float acc = 0.f;
        for (int m = 0; m < NN; ++m) acc += xsf[m] * S[m * NN + n];
        M[b * NN + n] = (acc + jterm) * (1.f / 3.f);
        wsum[b * NN + n] = ws_;
    }
}

// ---------------- K_wpack: reorder conv weights -> wpack[t][kh][pipe][c][kw] ----------------
__global__ __launch_bounds__(256) void k_wpack(const float* __restrict__ wm,
                                               const float* __restrict__ wx,
                                               float* __restrict__ wpack) {
    const int i = blockIdx.x * 256 + threadIdx.x;
    if (i >= TT * 72) return;
    const int t = i / 72;
    int r = i - t * 72;
    const int kh = r / 24; r -= kh * 24;
    const int pipe = r / 12; r -= pipe * 12;
    const int c = r / 3;
    const int kw = r - c * 3;
    const float* src = pipe ? wx : wm;
    wpack[i] = src[((c * TT + t) * 3 + kh) * 3 + kw];
}

// ---------------- K6 helpers ----------------
__device__ __forceinline__ void conv_load(const float* rp0, const float* rp1, const float* rp2,
                                          int voffA, int voffB, float4 F1[3], float4 F2[3]) {
    F1[0] = *reinterpret_cast<const float4*>(reinterpret_cast<const char*>(rp0) + voffA);
    F2[0] = *reinterpret_cast<const float4*>(reinterpret_cast<const char*>(rp0) + voffB);
    F1[1] = *reinterpret_cast<const float4*>(reinterpret_cast<const char*>(rp1) + voffA);
    F2[1] = *reinterpret_cast<const float4*>(reinterpret_cast<const char*>(rp1) + voffB);
    F1[2] = *reinterpret_cast<const float4*>(reinterpret_cast<const char*>(rp2) + voffA);
    F2[2] = *reinterpret_cast<const float4*>(reinterpret_cast<const char*>(rp2) + voffB);
}

// one (t,kh) step: issue next weight group into wq_fill, compute 96 FMAs from wq_use
__device__ __forceinline__ void kh_step(const float4& A1, const float4& A2,
                                        const float*& wp,
                                        float4 wq_fill[6], const float4 wq_use[6],
                                        bool wrap, float acc[8][4]) {
    // issue next weight group (independent of this step's FMAs -> no wait)
#pragma unroll
    for (int j = 0; j < 6; ++j)
        wq_fill[j] = *reinterpret_cast<const float4*>(wp + j * 4);
    wp += 24;

    const float wmv[12] = {wq_use[0].x, wq_use[0].y, wq_use[0].z, wq_use[0].w,
                           wq_use[1].x, wq_use[1].y, wq_use[1].z, wq_use[1].w,
                           wq_use[2].x, wq_use[2].y, wq_use[2].z, wq_use[2].w};
    const float wxv[12] = {wq_use[3].x, wq_use[3].y, wq_use[3].z, wq_use[3].w,
                           wq_use[4].x, wq_use[4].y, wq_use[4].z, wq_use[4].w,
                           wq_use[5].x, wq_use[5].y, wq_use[5].z, wq_use[5].w};
    const float i0 = A1.x, i1 = A1.y, i2 = A1.z, i3 = A1.w;
    const float i4 = wrap ? 0.f : A2.x;
    const float w30 = wrap ? 0.f : i3;
    const float w31 = A2.x, w32 = A2.y;
    const float win[4][3] = {{i0, i1, i2}, {i1, i2, i3}, {i2, i3, i4}, {w30, w31, w32}};
#pragma unroll
    for (int c = 0; c < 4; ++c) {
#pragma unroll
        for (int kw = 0; kw < 3; ++kw) {
            const float w1 = wmv[c * 3 + kw];
            const float w2 = wxv[c * 3 + kw];
#pragma unroll
            for (int v = 0; v < 4; ++v) {
                acc[c][v] = fmaf(win[v][kw], w1, acc[c][v]);
                acc[c + 4][v] = fmaf(win[v][kw], w2, acc[c + 4][v]);
            }
        }
    }
}

// ---------------- K6: fused dual conv — no LDS; data AND weight streams register-pipelined ----------------
__global__ __launch_bounds__(256, 2) void k_conv(const float* __restrict__ MPG,
                                                 const float* __restrict__ wpack,
                                                 const float* __restrict__ bmv,
                                                 const float* __restrict__ bxv,
                                                 const float* __restrict__ zrow,
                                                 float* __restrict__ partials) {
    const int b = blockIdx.y;
    const int r0 = blockIdx.x * 2;
    const int tid = threadIdx.x;
    const int ry = __builtin_amdgcn_readfirstlane(tid >> 7);  // wave-uniform
    const int tx = tid & 127;
    const int lane = tid & 63;
    const bool active = (tx < 125);
    const bool wrap = (tx == 124);

    // wave-uniform (SGPR) row pointers, advanced per t
    const float* rp0;
    const float* rp1;
    const float* rp2;
    int adv0, adv1, adv2;
    {
        const float* base = MPG + (size_t)b * (TT * NN * NN);
        const int g0 = r0 + ry - 1, g2 = r0 + ry + 1;
        const bool ok0 = (g0 >= 0), ok2 = (g2 < NN);
        rp0 = ok0 ? base + (size_t)g0 * NN : zrow;
        rp1 = base + (size_t)(r0 + ry) * NN;
        rp2 = ok2 ? base + (size_t)g2 * NN : zrow;
        adv0 = ok0 ? NN * NN : 0;
        adv1 = NN * NN;
        adv2 = ok2 ? NN * NN : 0;
    }
    const int voffA = active ? tx * 16 : 0;
    const int voffB = (active && !wrap) ? tx * 16 + 16 : 0;

    float acc[8][4];
#pragma unroll
    for (int c = 0; c < 4; ++c) {
        const float bm = bmv[c];
        const float bx = bxv[c];
#pragma unroll
        for (int v = 0; v < 4; ++v) {
            acc[c][v] = bm;
            acc[c + 4][v] = bx;
        }
    }

    float4 Fa1[3], Fa2[3], Fb1[3], Fb2[3];
    float4 wqA[6], wqB[6];
    const float* wp = wpack;

    // prologue: data t=0, weight group (t0,kh0)
    conv_load(rp0, rp1, rp2, voffA, voffB, Fa1, Fa2);
    rp0 += adv0; rp1 += adv1; rp2 += adv2;
#pragma unroll
    for (int j = 0; j < 6; ++j)
        wqA[j] = *reinterpret_cast<const float4*>(wp + j * 4);
    wp += 24;

#pragma unroll 1
    for (int t = 0; t < TT; t += 2) {
        // prefetch data t+1
        conv_load(rp0, rp1, rp2, voffA, voffB, Fb1, Fb2);
        rp0 += adv0; rp1 += adv1; rp2 += adv2;
        // t: three kh steps, weight ping-pong A->B->A
        kh_step(Fa1[0], Fa2[0], wp, wqB, wqA, wrap, acc);
        kh_step(Fa1[1], Fa2[1], wp, wqA, wqB, wrap, acc);
        kh_step(Fa1[2], Fa2[2], wp, wqB, wqA, wrap, acc);
        // prefetch data t+2
        if (t + 2 < TT) {
            conv_load(rp0, rp1, rp2, voffA, voffB, Fa1, Fa2);
            rp0 += adv0; rp1 += adv1; rp2 += adv2;
        }
        // t+1: three kh steps, B->A->B
        kh_step(Fb1[0], Fb2[0], wp, wqA, wqB, wrap, acc);
        kh_step(Fb1[1], Fb2[1], wp, wqB, wqA, wrap, acc);
        kh_step(Fb1[2], Fb2[2], wp, wqA, wqB, wrap, acc);
    }

    // relu + per-thread reduce
    float vals[8];
#pragma unroll
    for (int c = 0; c < 8; ++c) vals[c] = 0.f;
    if (active) {
#pragma unroll
        for (int c = 0; c < 4; ++c) {
            float s0 = 0.f;
#pragma unroll
            for (int v = 0; v < 4; ++v) s0 += fmaxf(acc[c][v], 0.f);
            vals[c] = s0;
            float m0 = 0.f;
#pragma unroll
            for (int v = 0; v < 4; ++v) m0 = fmaxf(m0, fmaxf(acc[c + 4][v], 0.f));
            vals[c + 4] = m0;
        }
    }

    // wave butterfly reduce
#pragma unroll
    for (int off = 32; off > 0; off >>= 1) {
#pragma unroll
        for (int c = 0; c < 4; ++c) vals[c] += __shfl_xor(vals[c], off, 64);
#pragma unroll
        for (int c = 4; c < 8; ++c) vals[c] = fmaxf(vals[c], __shfl_xor(vals[c], off, 64));
    }
    __shared__ float wred[4][8];
    const int wv = tid >> 6;
    if (lane == 0) {
#pragma unroll
        for (int c = 0; c < 8; ++c) wred[wv][c] = vals[c];
    }
    __syncthreads();
    if (tid < 8) {
        const float a0 = wred[0][tid], a1 = wred[1][tid], a2 = wred[2][tid], a3 = wred[3][tid];
        const float r = (tid < 4) ? (a0 + a1 + a2 + a3) : fmaxf(fmaxf(a0, a1), fmaxf(a2, a3));
        partials[((size_t)b * 250 + blockIdx.x) * 8 + tid] = r;
    }
}

// ---------------- K7: reduce partials -> topo[b][8] ----------------
__global__ __launch_bounds__(256) void k_topo(const float* __restrict__ partials,
                                              float* __restrict__ topo) {
    const int b = blockIdx.x;
    const int tid = threadIdx.x;
    const int c = tid & 7;
    const int g = tid >> 3;  // 32 groups
    float vs = 0.f, vm = 0.f;
    for (int rp = g; rp < 250; rp += 32) {
        const float v = partials[((size_t)b * 250 + rp) * 8 + c];
        vs += v;
        vm = fmaxf(vm, v);
    }
    __shared__ float red[256];
    red[tid] = (c < 4) ? vs : vm;
    __syncthreads();
    for (int s = 16; s > 0; s >>= 1) {
        if (g < s) {
            const float a = red[tid];
            const float bv = red[tid + s * 8];
            red[tid] = (c < 4) ? (a + bv) : fmaxf(a, bv);
        }
        __syncthreads();
    }
    if (tid < 8) topo[b * 8 + tid] = (tid < 4) ? red[tid] * (1.f / (NN * (float)NN)) : red[tid];
}

// ---------------- K8: assemble output ----------------
__global__ __launch_bounds__(64) void k_out(const float* __restrict__ x,
                                            const float* __restrict__ y1,
                                            const float* __restrict__ y2,
                                            const float* __restrict__ W,
                                            const float* __restrict__ biasN,
                                            const float* __restrict__ wws,
                                            const float* __restrict__ wwt,
                                            const float* __restrict__ M,
                                            const float* __restrict__ wsum,
                                            const float* __restrict__ topo,
                                            float* __restrict__ out) {
    const int bn = blockIdx.x;
    const int b = bn / NN;
    const int n = bn - b * NN;
    const int o = threadIdx.x;
    float val;
    if (o < 48) {
        val = x[bn] * W[n * 144 + o] + y1[bn] * W[n * 144 + 48 + o] + y2[bn] * W[n * 144 + 96 + o];
    } else if (o < 56) {
        const int oo = o - 48;
        val = M[bn] * wws[n * 8 + oo] * topo[b * 8 + oo];
    } else {
        const int oo = o - 56;
        val = wsum[bn] * wwt[n * 8 + oo];
    }
    out[(size_t)bn * 64 + o] = val + biasN[n * 64 + o];
}

extern "C" void kernel_launch(void* const* d_in, const int* in_sizes, int n_in,
                              void* d_out, int out_size, void* d_ws, size_t ws_size,
                              hipStream_t stream) {
    const float* x    = (const float*)d_in[0];
    const float* xw   = (const float*)d_in[1];
    const float* E    = (const float*)d_in[2];
    const float* MPG  = (const float*)d_in[4];
    const int*   bidx = (const int*)d_in[5];
    const int*   stay = (const int*)d_in[7];
    const int*   jump = (const int*)d_in[8];
    const float* wp   = (const float*)d_in[9];
    const float* wwsp = (const float*)d_in[10];
    const float* wwtp = (const float*)d_in[11];
    const float* bp   = (const float*)d_in[12];
    const float* Tp   = (const float*)d_in[13];
    const float* cmw  = (const float*)d_in[14];
    const float* cmb  = (const float*)d_in[15];
    const float* cxw  = (const float*)d_in[16];
    const float* cxb  = (const float*)d_in[17];
    float* out = (float*)d_out;

    float* w = (float*)d_ws;
    float* S     = w;               // 250000
    float* y1    = S + 250000;      // 16000
    float* y2    = y1 + 16000;      // 16000
    float* W     = y2 + 16000;      // 72000
    float* biasN = W + 72000;       // 32000
    float* wws   = biasN + 32000;   // 4000
    float* wwt   = wws + 4000;      // 4000
    float* M     = wwt + 4000;      // 16000
    float* wsum  = M + 16000;       // 16000
    float* parts = wsum + 16000;    // 64000
    float* topo  = parts + 64000;   // 256
    float* zrow  = topo + 256;      // 640 floats zero page
    float* wpck  = zrow + 640;      // 864 packed weights + 24 pad (prefetch overshoot)

    hipMemsetAsync(zrow, 0, 640 * sizeof(float), stream);
    k_wpack<<<4, 256, 0, stream>>>(cmw, cxw, wpck);
    k_softmaxS<<<NN, 256, 0, stream>>>(E, stay, S);
    k_matvecS<<<dim3(125, BB), 256, 0, stream>>>(S, x, y1);
    k_matvecS<<<dim3(125, BB), 256, 0, stream>>>(S, y1, y2);
    k_smallpre<<<NN, 256, 0, stream>>>(E, wp, bp, wwsp, wwtp, W, biasN, wws, wwt);
    k_Mwsum<<<dim3(4, BB), 128, 0, stream>>>(xw, S, bidx, jump, Tp, M, wsum);
    k_conv<<<dim3(250, BB), 256, 0, stream>>>(MPG, wpck, cmb, cxb, zrow, parts);
    k_topo<<<BB, 256, 0, stream>>>(parts, topo);
    k_out<<<BB * NN, 64, 0, stream>>>(x, y1, y2, W, biasN, wws, wwt, M, wsum, topo, out);
}

// Round 8
// 228.510 us; speedup vs baseline: 1.0226x; 1.0226x over previous
//
#include <hip/hip_runtime.h>

#define NN 500
#define BB 32
#define TT 12
#define EMB 10

typedef float f2v __attribute__((ext_vector_type(2)));

// ---------------- K1: S = softmax(relu(E E^T) with diag=stay), rows ----------------
__global__ __launch_bounds__(256) void k_softmaxS(const float* __restrict__ E,
                                                  const int* __restrict__ stay,
                                                  float* __restrict__ S) {
    const int i = blockIdx.x;
    const int tid = threadIdx.x;
    __shared__ float row[NN];
    __shared__ float red[256];
    float ei[EMB];
#pragma unroll
    for (int d = 0; d < EMB; ++d) ei[d] = E[i * EMB + d];
    const float stayf = (float)stay[0];

    float lmax = -1e30f;
    for (int j = tid; j < NN; j += 256) {
        float acc = 0.f;
#pragma unroll
        for (int d = 0; d < EMB; ++d) acc += ei[d] * E[j * EMB + d];
        float v = acc > 0.f ? acc : 0.f;
        if (j == i) v = stayf;
        row[j] = v;
        lmax = fmaxf(lmax, v);
    }
    red[tid] = lmax;
    __syncthreads();
    for (int s = 128; s > 0; s >>= 1) {
        if (tid < s) red[tid] = fmaxf(red[tid], red[tid + s]);
        __syncthreads();
    }
    const float rmax = red[0];
    __syncthreads();

    float lsum = 0.f;
    for (int j = tid; j < NN; j += 256) {
        float e = __expf(row[j] - rmax);
        row[j] = e;
        lsum += e;
    }
    red[tid] = lsum;
    __syncthreads();
    for (int s = 128; s > 0; s >>= 1) {
        if (tid < s) red[tid] += red[tid + s];
        __syncthreads();
    }
    const float inv = 1.0f / red[0];
    for (int j = tid; j < NN; j += 256) S[i * NN + j] = row[j] * inv;
}

// ---------------- K2/K3: y[b,n] = sum_m S[n,m] * xin[b,m] (wave per row) ----------------
__global__ __launch_bounds__(256) void k_matvecS(const float* __restrict__ S,
                                                 const float* __restrict__ xin,
                                                 float* __restrict__ yout) {
    const int b = blockIdx.y;
    const int w = threadIdx.x >> 6;
    const int lane = threadIdx.x & 63;
    const int n = blockIdx.x * 4 + w;
    const float* xb = xin + b * NN;
    const float* Sr = S + n * NN;
    float acc = 0.f;
    for (int m = lane; m < NN; m += 64) acc += Sr[m] * xb[m];
#pragma unroll
    for (int off = 32; off > 0; off >>= 1) acc += __shfl_down(acc, off, 64);
    if (lane == 0) yout[b * NN + n] = acc;
}

// ---------------- K4: per-node small weights from embeddings ----------------
__global__ __launch_bounds__(256) void k_smallpre(const float* __restrict__ E,
                                                  const float* __restrict__ wp,
                                                  const float* __restrict__ bp,
                                                  const float* __restrict__ wwsp,
                                                  const float* __restrict__ wwtp,
                                                  float* __restrict__ W,
                                                  float* __restrict__ biasN,
                                                  float* __restrict__ wws,
                                                  float* __restrict__ wwt) {
    const int n = blockIdx.x;
    const int tid = threadIdx.x;
    __shared__ float e[EMB];
    if (tid < EMB) e[tid] = E[n * EMB + tid];
    __syncthreads();
    if (tid < 144) {
        float acc = 0.f;
#pragma unroll
        for (int d = 0; d < EMB; ++d) acc += e[d] * wp[d * 144 + tid];
        W[n * 144 + tid] = acc;
    } else if (tid < 208) {
        const int o = tid - 144;
        float acc = 0.f;
#pragma unroll
        for (int d = 0; d < EMB; ++d) acc += e[d] * bp[d * 64 + o];
        biasN[n * 64 + o] = acc;
    } else if (tid < 216) {
        const int o = tid - 208;
        float acc = 0.f;
#pragma unroll
        for (int d = 0; d < EMB; ++d) acc += e[d] * wwsp[d * 8 + o];
        wws[n * 8 + o] = acc;
    } else if (tid < 224) {
        const int o = tid - 216;
        float acc = 0.f;
#pragma unroll
        for (int d = 0; d < EMB; ++d) acc += e[d] * wwtp[d * 8 + o];
        wwt[n * 8 + o] = acc;
    }
}

// ---------------- K5: M[b,n] = mean_f xws, wsum[b,n] = sum_t xw[b,t,n]*T[t] ----------------
__global__ __launch_bounds__(128) void k_Mwsum(const float* __restrict__ xwin,
                                               const float* __restrict__ S,
                                               const int* __restrict__ bidx,
                                               const int* __restrict__ jumpc,
                                               const float* __restrict__ Tp,
                                               float* __restrict__ M,
                                               float* __restrict__ wsum) {
    const int b = blockIdx.y;
    const int n0 = blockIdx.x * 125;
    const int tid = threadIdx.x;
    __shared__ float xsf[NN];
    __shared__ float Tl[TT];
    const int t0 = bidx[0], t1 = bidx[1], t2 = bidx[2];
    if (tid < TT) Tl[tid] = Tp[tid];
    const float* xb = xwin + (size_t)b * TT * NN;
    for (int m = tid; m < NN; m += 128)
        xsf[m] = xb[t0 * NN + m] + xb[t1 * NN + m] + xb[t2 * NN + m];
    __syncthreads();
    if (tid < 125) {
        const int n = n0 + tid;
        float ws_ = 0.f;
#pragma unroll
        for (int t = 0; t < TT; ++t) ws_ += xb[t * NN + n] * Tl[t];
        const float jc = (float)jumpc[0];
        const float jterm = jc * (2.f * xb[t0 * NN + n] + xb[t1 * NN + n]);
        float acc = 0.f;
        for (int m = 0; m < NN; ++m) acc += xsf[m] * S[m * NN + n];
        M[b * NN + n] = (acc + jterm) * (1.f / 3.f);
        wsum[b * NN + n] = ws_;
    }
}

// ---------------- K_wpack: duplicate-pack conv weights -> wpack2[t][kh][pipe][c][kw][2] ----------------
__global__ __launch_bounds__(256) void k_wpack(const float* __restrict__ wm,
                                               const float* __restrict__ wx,
                                               float* __restrict__ wpack2) {
    const int i = blockIdx.x * 256 + threadIdx.x;
    if (i >= TT * 3 * 2 * 4 * 3 * 2) return;
    int k = i >> 1;  // [t][kh][pipe][c][kw]
    const int kw = k % 3; k /= 3;
    const int c = k % 4; k /= 4;
    const int pipe = k % 2; k /= 2;
    const int kh = k % 3;
    const int t = k / 3;
    const float* src = pipe ? wx : wm;
    wpack2[i] = src[((c * TT + t) * 3 + kh) * 3 + kw];
}

// ---------------- K6 helpers ----------------
__device__ __forceinline__ void load9(const float* rp0, const float* rp1, const float* rp2,
                                      int voffA, int voffB, int voffC, float4 F[3][3]) {
    const char* p0 = reinterpret_cast<const char*>(rp0);
    const char* p1 = reinterpret_cast<const char*>(rp1);
    const char* p2 = reinterpret_cast<const char*>(rp2);
    F[0][0] = *reinterpret_cast<const float4*>(p0 + voffA);
    F[0][1] = *reinterpret_cast<const float4*>(p0 + voffB);
    F[0][2] = *reinterpret_cast<const float4*>(p0 + voffC);
    F[1][0] = *reinterpret_cast<const float4*>(p1 + voffA);
    F[1][1] = *reinterpret_cast<const float4*>(p1 + voffB);
    F[1][2] = *reinterpret_cast<const float4*>(p1 + voffC);
    F[2][0] = *reinterpret_cast<const float4*>(p2 + voffA);
    F[2][1] = *reinterpret_cast<const float4*>(p2 + voffB);
    F[2][2] = *reinterpret_cast<const float4*>(p2 + voffC);
}

// one t: 3 kh steps, 8ch x 4 col-pairs, packed fp32
__device__ __forceinline__ void conv_body(const float4 F[3][3],
                                          const float* __restrict__ wb,
                                          bool wrap, f2v acc2[8][4]) {
#pragma unroll
    for (int kh = 0; kh < 3; ++kh) {
        float4 wq[12];
#pragma unroll
        for (int j = 0; j < 12; ++j)
            wq[j] = *reinterpret_cast<const float4*>(wb + kh * 48 + j * 4);

        const float4 q0 = F[kh][0], q1 = F[kh][1], q2 = F[kh][2];
        // e[0..8]: input cols base..base+8 (with e[4] zero-padded for the wrap thread)
        float e[9];
        e[0] = q0.x; e[1] = q0.y; e[2] = q0.z; e[3] = q0.w;
        e[4] = wrap ? 0.f : q1.x;
        e[5] = q1.y; e[6] = q1.z; e[7] = q1.w; e[8] = q2.x;
        // v=7 window (repurposed as col 0 on the wrap thread; q1/q2 load cols 0..3 there)
        const float v7w[3] = {wrap ? 0.f : q1.w, q2.x, q2.y};

#pragma unroll
        for (int kw = 0; kw < 3; ++kw) {
            f2v win[4];
            win[0] = f2v{e[kw], e[kw + 1]};
            win[1] = f2v{e[2 + kw], e[3 + kw]};
            win[2] = f2v{e[4 + kw], e[5 + kw]};
            win[3] = f2v{e[6 + kw], v7w[kw]};
#pragma unroll
            for (int c = 0; c < 4; ++c) {
                const int km = c * 3 + kw;        // mean weight pair index
                const int kx = 12 + c * 3 + kw;   // max weight pair index
                const float4 qm = wq[km >> 1];
                const float4 qx = wq[kx >> 1];
                const f2v wm2 = (km & 1) ? f2v{qm.z, qm.w} : f2v{qm.x, qm.y};
                const f2v wx2 = (kx & 1) ? f2v{qx.z, qx.w} : f2v{qx.x, qx.y};
#pragma unroll
                for (int p = 0; p < 4; ++p) {
                    acc2[c][p] = __builtin_elementwise_fma(win[p], wm2, acc2[c][p]);
                    acc2[c + 4][p] = __builtin_elementwise_fma(win[p], wx2, acc2[c + 4][p]);
                }
            }
        }
    }
}

// ---------------- K6: fused dual conv — 4 rows/block, 8 cols/thread, packed fp32, no LDS ----------------
__global__ __launch_bounds__(256, 2) void k_conv(const float* __restrict__ MPG,
                                                 const float* __restrict__ wpack2,
                                                 const float* __restrict__ bmv,
                                                 const float* __restrict__ bxv,
                                                 const float* __restrict__ zrow,
                                                 float* __restrict__ partials) {
    const int b = blockIdx.y;
    const int r0 = blockIdx.x * 4;
    const int tid = threadIdx.x;
    const int ry = __builtin_amdgcn_readfirstlane(tid >> 6);  // wave-uniform row 0..3
    const int tx = tid & 63;
    const bool active = (tx < 63);
    const bool wrap = (tx == 62);

    // wave-uniform (SGPR) row pointers
    const float* rp0;
    const float* rp1;
    const float* rp2;
    int adv0, adv1, adv2;
    {
        const float* base = MPG + (size_t)b * (TT * NN * NN);
        const int g0 = r0 + ry - 1, g2 = r0 + ry + 1;
        const bool ok0 = (g0 >= 0), ok2 = (g2 < NN);
        rp0 = ok0 ? base + (size_t)g0 * NN : zrow;
        rp1 = base + (size_t)(r0 + ry) * NN;
        rp2 = ok2 ? base + (size_t)g2 * NN : zrow;
        adv0 = ok0 ? NN * NN : 0;
        adv1 = NN * NN;
        adv2 = ok2 ? NN * NN : 0;
    }
    // thread covers output cols 8tx+1 .. 8tx+8 (wrap thread: 497,498,499 + col 0)
    const int voffA = active ? tx * 32 : 0;
    const int voffB = (active && !wrap) ? tx * 32 + 16 : 0;
    const int voffC = (active && !wrap) ? tx * 32 + 32 : 0;

    f2v acc2[8][4];
#pragma unroll
    for (int c = 0; c < 4; ++c) {
        const float bm = bmv[c];
        const float bx = bxv[c];
#pragma unroll
        for (int p = 0; p < 4; ++p) {
            acc2[c][p] = f2v{bm, bm};
            acc2[c + 4][p] = f2v{bx, bx};
        }
    }

    float4 Fa[3][3], Fb[3][3];
    load9(rp0, rp1, rp2, voffA, voffB, voffC, Fa);
    rp0 += adv0; rp1 += adv1; rp2 += adv2;

#pragma unroll 1
    for (int t = 0; t < TT; t += 2) {
        load9(rp0, rp1, rp2, voffA, voffB, voffC, Fb);
        rp0 += adv0; rp1 += adv1; rp2 += adv2;
        conv_body(Fa, wpack2 + t * 144, wrap, acc2);
        if (t + 2 < TT) {
            load9(rp0, rp1, rp2, voffA, voffB, voffC, Fa);
            rp0 += adv0; rp1 += adv1; rp2 += adv2;
        }
        conv_body(Fb, wpack2 + (t + 1) * 144, wrap, acc2);
    }

    // per-slot validity masks (relu>=0 makes mask-by-zero safe for both sum and max)
    float mk[8];
#pragma unroll
    for (int v = 0; v < 8; ++v) {
        const bool ok = active && (!wrap || v < 3 || v == 7);
        mk[v] = ok ? 1.f : 0.f;
    }

    float vals[8];
#pragma unroll
    for (int c = 0; c < 4; ++c) {
        float s0 = 0.f, m0 = 0.f;
#pragma unroll
        for (int p = 0; p < 4; ++p) {
            const float a0 = fmaxf(acc2[c][p].x, 0.f) * mk[2 * p];
            const float a1 = fmaxf(acc2[c][p].y, 0.f) * mk[2 * p + 1];
            s0 += a0 + a1;
            const float b0 = fmaxf(acc2[c + 4][p].x, 0.f) * mk[2 * p];
            const float b1 = fmaxf(acc2[c + 4][p].y, 0.f) * mk[2 * p + 1];
            m0 = fmaxf(m0, fmaxf(b0, b1));
        }
        vals[c] = s0;
        vals[c + 4] = m0;
    }

    // wave butterfly reduce (one wave per output row)
#pragma unroll
    for (int off = 32; off > 0; off >>= 1) {
#pragma unroll
        for (int c = 0; c < 4; ++c) vals[c] += __shfl_xor(vals[c], off, 64);
#pragma unroll
        for (int c = 4; c < 8; ++c) vals[c] = fmaxf(vals[c], __shfl_xor(vals[c], off, 64));
    }
    __shared__ float wred[4][8];
    const int wv = tid >> 6;
    if (tx == 0) {
#pragma unroll
        for (int c = 0; c < 8; ++c) wred[wv][c] = vals[c];
    }
    __syncthreads();
    if (tid < 8) {
        const float a0 = wred[0][tid], a1 = wred[1][tid], a2 = wred[2][tid], a3 = wred[3][tid];
        const float r = (tid < 4) ? (a0 + a1 + a2 + a3) : fmaxf(fmaxf(a0, a1), fmaxf(a2, a3));
        partials[((size_t)b * 125 + blockIdx.x) * 8 + tid] = r;
    }
}

// ---------------- K7: reduce partials -> topo[b][8] ----------------
__global__ __launch_bounds__(256) void k_topo(const float* __restrict__ partials,
                                              float* __restrict__ topo) {
    const int b = blockIdx.x;
    const int tid = threadIdx.x;
    const int c = tid & 7;
    const int g = tid >> 3;  // 32 groups
    float vs = 0.f, vm = 0.f;
    for (int rp = g; rp < 125; rp += 32) {
        const float v = partials[((size_t)b * 125 + rp) * 8 + c];
        vs += v;
        vm = fmaxf(vm, v);
    }
    __shared__ float red[256];
    red[tid] = (c < 4) ? vs : vm;
    __syncthreads();
    for (int s = 16; s > 0; s >>= 1) {
        if (g < s) {
            const float a = red[tid];
            const float bv = red[tid + s * 8];
            red[tid] = (c < 4) ? (a + bv) : fmaxf(a, bv);
        }
        __syncthreads();
    }
    if (tid < 8) topo[b * 8 + tid] = (tid < 4) ? red[tid] * (1.f / (NN * (float)NN)) : red[tid];
}

// ---------------- K8: assemble output ----------------
__global__ __launch_bounds__(64) void k_out(const float* __restrict__ x,
                                            const float* __restrict__ y1,
                                            const float* __restrict__ y2,
                                            const float* __restrict__ W,
                                            const float* __restrict__ biasN,
                                            const float* __restrict__ wws,
                                            const float* __restrict__ wwt,
                                            const float* __restrict__ M,
                                            const float* __restrict__ wsum,
                                            const float* __restrict__ topo,
                                            float* __restrict__ out) {
    const int bn = blockIdx.x;
    const int b = bn / NN;
    const int n = bn - b * NN;
    const int o = threadIdx.x;
    float val;
    if (o < 48) {
        val = x[bn] * W[n * 144 + o] + y1[bn] * W[n * 144 + 48 + o] + y2[bn] * W[n * 144 + 96 + o];
    } else if (o < 56) {
        const int oo = o - 48;
        val = M[bn] * wws[n * 8 + oo] * topo[b * 8 + oo];
    } else {
        const int oo = o - 56;
        val = wsum[bn] * wwt[n * 8 + oo];
    }
    out[(size_t)bn * 64 + o] = val + biasN[n * 64 + o];
}

extern "C" void kernel_launch(void* const* d_in, const int* in_sizes, int n_in,
                              void* d_out, int out_size, void* d_ws, size_t ws_size,
                              hipStream_t stream) {
    const float* x    = (const float*)d_in[0];
    const float* xw   = (const float*)d_in[1];
    const float* E    = (const float*)d_in[2];
    const float* MPG  = (const float*)d_in[4];
    const int*   bidx = (const int*)d_in[5];
    const int*   stay = (const int*)d_in[7];
    const int*   jump = (const int*)d_in[8];
    const float* wp   = (const float*)d_in[9];
    const float* wwsp = (const float*)d_in[10];
    const float* wwtp = (const float*)d_in[11];
    const float* bp   = (const float*)d_in[12];
    const float* Tp   = (const float*)d_in[13];
    const float* cmw  = (const float*)d_in[14];
    const float* cmb  = (const float*)d_in[15];
    const float* cxw  = (const float*)d_in[16];
    const float* cxb  = (const float*)d_in[17];
    float* out = (float*)d_out;

    float* w = (float*)d_ws;
    float* S     = w;               // 250000
    float* y1    = S + 250000;      // 16000
    float* y2    = y1 + 16000;      // 16000
    float* W     = y2 + 16000;      // 72000
    float* biasN = W + 72000;       // 32000
    float* wws   = biasN + 32000;   // 4000
    float* wwt   = wws + 4000;      // 4000
    float* M     = wwt + 4000;      // 16000
    float* wsum  = M + 16000;       // 16000
    float* parts = wsum + 16000;    // 32000
    float* topo  = parts + 32000;   // 256
    float* zrow  = topo + 256;      // 640 floats zero page
    float* wpck  = zrow + 640;      // 1728 packed duplicated weights + pad

    hipMemsetAsync(zrow, 0, 640 * sizeof(float), stream);
    k_wpack<<<7, 256, 0, stream>>>(cmw, cxw, wpck);
    k_softmaxS<<<NN, 256, 0, stream>>>(E, stay, S);
    k_matvecS<<<dim3(125, BB), 256, 0, stream>>>(S, x, y1);
    k_matvecS<<<dim3(125, BB), 256, 0, stream>>>(S, y1, y2);
    k_smallpre<<<NN, 256, 0, stream>>>(E, wp, bp, wwsp, wwtp, W, biasN, wws, wwt);
    k_Mwsum<<<dim3(4, BB), 128, 0, stream>>>(xw, S, bidx, jump, Tp, M, wsum);
    k_conv<<<dim3(125, BB), 256, 0, stream>>>(MPG, wpck, cmb, cxb, zrow, parts);
    k_topo<<<BB, 256, 0, stream>>>(parts, topo);
    k_out<<<BB * NN, 64, 0, stream>>>(x, y1, y2, W, biasN, wws, wwt, M, wsum, topo, out);
}